// Round 3
// baseline (101.785 us; speedup 1.0000x reference)
//
#include <hip/hip_runtime.h>
#include <stdint.h>

#define BATCH   2048
#define INDIM   512
#define OUTDIM  512
#define SDIM    8

typedef __attribute__((ext_vector_type(4))) float  f32x4;
typedef __attribute__((ext_vector_type(8))) __bf16 bf16x8;
typedef __attribute__((ext_vector_type(8))) unsigned short u16x8;

__device__ __forceinline__ unsigned short f2bf(float x) {
  unsigned int u = __float_as_uint(x);
  u += 0x7fffu + ((u >> 16) & 1u);      // round-to-nearest-even
  return (unsigned short)(u >> 16);
}

__device__ __forceinline__ void llds16(const void* g, void* s) {
  __builtin_amdgcn_global_load_lds(
      (__attribute__((address_space(1))) void*)g,
      (__attribute__((address_space(3))) void*)s, 16, 0, 0);
}

// ---------------------------------------------------------------------------
// prep: blocks [0,512) each handle 4 batch rows: Fbf[b,i]=bf16(feat[b,i]),
// basisArr[b,s]=fp32 basis, out[b,:]=basis@b_wts (bias init, replaces memset).
// Blocks [512,1024): transpose W into per-s Bt: Bt[s][n][k]=W[s,k,n] bf16.
// ---------------------------------------------------------------------------
__global__ __launch_bounds__(256) void prep_kernel(
    const float* __restrict__ inp, const float* __restrict__ W,
    const float* __restrict__ bwts, unsigned short* __restrict__ Fbf,
    unsigned short* __restrict__ Btf, float* __restrict__ basisArr,
    float* __restrict__ out) {
  const int tid = threadIdx.x;
  const int bx  = blockIdx.x;
  if (bx < 512) {
    const int r = bx * 4 + (tid >> 6);   // batch row
    const int l = tid & 63;
    const float* row = inp + (size_t)r * (INDIM + 1);
    const float t = row[0];
    float bs[8];
    bs[0] = 1.0f; bs[1] = t; bs[2] = t * t; bs[3] = bs[2] * t;
    const float kn[4] = {0.2f, 0.4f, 0.6f, 0.8f};
#pragma unroll
    for (int c = 0; c < 4; ++c) {
      float d = fmaxf(t - kn[c], 0.0f);
      bs[4 + c] = d * d * d;
    }
    const int c = l * 8;
    // feat -> bf16 (scalar loads: inp row stride 513 breaks 16B alignment)
    u16x8 o;
#pragma unroll
    for (int q = 0; q < 8; ++q) o[q] = f2bf(row[1 + c + q]);
    *(u16x8*)&Fbf[(size_t)r * INDIM + c] = o;
    if (l < 8) basisArr[r * 8 + l] = bs[l];
    // bias init: out[r, c..c+7] = sum_s bs[s] * b_wts[s, c..c+7]
    f32x4 a0 = {}, a1 = {};
#pragma unroll
    for (int s = 0; s < 8; ++s) {
      f32x4 w0 = *(const f32x4*)&bwts[s * OUTDIM + c];
      f32x4 w1 = *(const f32x4*)&bwts[s * OUTDIM + c + 4];
      a0 += w0 * bs[s]; a1 += w1 * bs[s];
    }
    *(f32x4*)&out[(size_t)r * OUTDIM + c]     = a0;
    *(f32x4*)&out[(size_t)r * OUTDIM + c + 4] = a1;
  } else {
    const int bb = bx - 512;             // 0..511
    const int kt = bb >> 3, nt = bb & 7;
    const int ks0 = kt * 64, n0 = nt * 64;   // global k in [0,4096)
    const int s = ks0 >> 9, kloc0 = ks0 & 511;
    __shared__ float Ts[64][65];         // [n_local][k_local], padded
#pragma unroll
    for (int p = 0; p < 4; ++p) {
      const int r  = (tid >> 4) + p * 16;  // k-local
      const int c4 = (tid & 15) * 4;       // n-local
      float4 v = *(const float4*)&W[(size_t)(ks0 + r) * 512 + n0 + c4];
      Ts[c4 + 0][r] = v.x; Ts[c4 + 1][r] = v.y;
      Ts[c4 + 2][r] = v.z; Ts[c4 + 3][r] = v.w;
    }
    __syncthreads();
    const int nl  = tid >> 2;            // 0..63
    const int kcc = (tid & 3) * 16;      // 0,16,32,48
    u16x8 o0, o1;
#pragma unroll
    for (int q = 0; q < 8; ++q) {
      o0[q] = f2bf(Ts[nl][kcc + q]);
      o1[q] = f2bf(Ts[nl][kcc + 8 + q]);
    }
    unsigned short* dst = Btf + (size_t)s * (512 * 512)
                        + (size_t)(n0 + nl) * 512 + kloc0 + kcc;
    *(u16x8*)dst = o0;
    *(u16x8*)(dst + 8) = o1;
  }
}

// ---------------------------------------------------------------------------
// GEMM: for s = blockIdx&7: P = F(2048x512) @ Bt_s^T, out += basis[:,s] * P.
// 128x128 tile, 4 waves each 64x64 (4x4 mfma frags), BK=64, 8 k-steps.
// Split over s => 512 blocks (2/CU). XCD swizzle: s = blk&7 so each XCD's
// working set = F (2MB) + Bt_s (0.5MB) < 4MiB L2.
// global_load_lds(16B) staging with XOR swizzle (chunk ^= row&7) on the
// GLOBAL source so the LDS dst stays wave-uniform-base + lane*16.
// Epilogue: fp32 scale by basisArr[row,s], unsafeAtomicAdd into out.
// ---------------------------------------------------------------------------
__global__ __launch_bounds__(256, 2) void gemm_kernel(
    const unsigned short* __restrict__ Fbf,
    const unsigned short* __restrict__ Btf,
    const float* __restrict__ basisArr,
    float* __restrict__ out) {
  const int tid  = threadIdx.x;
  const int s    = blockIdx.x & 7;
  const int slot = blockIdx.x >> 3;      // 0..63
  const int nt = slot & 3, mt = slot >> 2;
  const int m0 = mt * 128, n0 = nt * 128;
  const int l = tid & 63, w = tid >> 6;
  const int wm = w >> 1, wn = w & 1;
  const int quad = l >> 4, lr = l & 15, sx = lr & 7;

  __shared__ __align__(16) unsigned short As[128 * 64];
  __shared__ __align__(16) unsigned short Bs[128 * 64];

  f32x4 acc[4][4] = {};

  // staging: thread t -> rows sr+32p (p=0..3), 16B chunk pc; XOR swizzle picks
  // the global chunk lc = pc ^ (row&7); LDS side is lane-contiguous.
  const int sr = tid >> 3, pc = tid & 7;
  const int lc = pc ^ (sr & 7);
  const unsigned short* Fg = Fbf + (size_t)(m0 + sr) * 512 + lc * 8;
  const unsigned short* Bg = Btf + (size_t)s * (512 * 512)
                           + (size_t)(n0 + sr) * 512 + lc * 8;
  unsigned short* AsW = &As[sr * 64 + pc * 8];
  unsigned short* BsW = &Bs[sr * 64 + pc * 8];

  for (int it = 0; it < 8; ++it) {
    const int i0 = it * 64;
#pragma unroll
    for (int p = 0; p < 4; ++p) {
      llds16(Fg + i0 + p * 32 * 512, AsW + p * 2048);
      llds16(Bg + i0 + p * 32 * 512, BsW + p * 2048);
    }
    __syncthreads();
#pragma unroll
    for (int ks = 0; ks < 2; ++ks) {
      const int ch = ((ks * 4 + quad) ^ sx) * 8;
      bf16x8 af[4], bfr[4];
#pragma unroll
      for (int mf = 0; mf < 4; ++mf)
        af[mf] = *(const bf16x8*)&As[(wm * 64 + mf * 16 + lr) * 64 + ch];
#pragma unroll
      for (int nf = 0; nf < 4; ++nf)
        bfr[nf] = *(const bf16x8*)&Bs[(wn * 64 + nf * 16 + lr) * 64 + ch];
#pragma unroll
      for (int mf = 0; mf < 4; ++mf)
#pragma unroll
        for (int nf = 0; nf < 4; ++nf)
          acc[mf][nf] = __builtin_amdgcn_mfma_f32_16x16x32_bf16(
              af[mf], bfr[nf], acc[mf][nf], 0, 0, 0);
    }
    __syncthreads();
  }

  // C/D layout (verified m89/m91): col = lane&15, row = (lane>>4)*4 + reg
#pragma unroll
  for (int mf = 0; mf < 4; ++mf) {
    const int rb = m0 + wm * 64 + mf * 16 + quad * 4;
    float bsv[4];
#pragma unroll
    for (int r = 0; r < 4; ++r) bsv[r] = basisArr[(rb + r) * 8 + s];
#pragma unroll
    for (int nf = 0; nf < 4; ++nf) {
      const int col = n0 + wn * 64 + nf * 16 + lr;
#pragma unroll
      for (int r = 0; r < 4; ++r)
        unsafeAtomicAdd(out + (size_t)(rb + r) * OUTDIM + col,
                        bsv[r] * acc[mf][nf][r]);
    }
  }
}

extern "C" void kernel_launch(void* const* d_in, const int* in_sizes, int n_in,
                              void* d_out, int out_size, void* d_ws, size_t ws_size,
                              hipStream_t stream) {
  const float* inp  = (const float*)d_in[0];   // (2048, 513)
  const float* W    = (const float*)d_in[1];   // (8, 262144): (s,i,o)
  const float* bwts = (const float*)d_in[2];   // (8, 512)
  float* out = (float*)d_out;

  unsigned short* Fbf = (unsigned short*)d_ws;               // 2048*512 bf16
  unsigned short* Btf = Fbf + (size_t)BATCH * INDIM;         // 8*512*512 bf16
  float* basisArr = (float*)(Btf + (size_t)SDIM * 512 * 512); // 2048*8 f32

  prep_kernel<<<1024, 256, 0, stream>>>(inp, W, bwts, Fbf, Btf, basisArr, out);
  gemm_kernel<<<512, 256, 0, stream>>>(Fbf, Btf, basisArr, out);
}